// Round 1
// baseline (9194.161 us; speedup 1.0000x reference)
//
#include <hip/hip_runtime.h>
#include <cstdint>

#define B_ 64
#define T_ 4096
#define D_ 67
#define H_ 128
#define N_ 512            // 4*H: [ff1 | ff2 | ta | tb]
#define TOK_ (B_*T_)

typedef _Float16 zfp;     // z_x stored fp16: halves ws + HBM, ~1e-3 abs err

__device__ __forceinline__ float sigm(float x){ return 1.0f/(1.0f+__expf(-x)); }
__device__ __forceinline__ float tanh_(float x){ return 1.0f - 2.0f/(__expf(2.0f*x)+1.0f); }

// ---------------------------------------------------------------------------
// Stage A (parallel): per token LN(67) -> proj(67->128) -> LN(128) -> SiLU
//   -> z_x[token, 0:512] = feat @ W_top + bias_cat   (fp16 to d_ws)
// 256 persistent WGs x 512 threads; W_top column (128 f32) per thread in VGPRs.
// ---------------------------------------------------------------------------
__global__ __launch_bounds__(512, 2)
void stage_a(const float* __restrict__ x,
             const float* __restrict__ g_in, const float* __restrict__ b_in,
             const float* __restrict__ proj_w, const float* __restrict__ proj_b,
             const float* __restrict__ g_p, const float* __restrict__ b_p,
             const float* __restrict__ ff1_w, const float* __restrict__ ff1_b,
             const float* __restrict__ ff2_w, const float* __restrict__ ff2_b,
             const float* __restrict__ ta_w, const float* __restrict__ ta_b,
             const float* __restrict__ tb_w, const float* __restrict__ tb_b,
             zfp* __restrict__ zx)
{
  __shared__ float pw[D_*H_];                 // proj_w staged (33.5 KB)
  __shared__ __align__(16) float feat[H_];
  __shared__ float xn[D_];
  __shared__ float red[4];
  const int tid = threadIdx.x;

  for (int i = tid; i < D_*H_; i += 512) pw[i] = proj_w[i];

  const int n = tid, m = n >> 7, j = n & 127;
  const float* wmat = (m==0)?ff1_w:(m==1)?ff2_w:(m==2)?ta_w:tb_w;
  const float* bvec = (m==0)?ff1_b:(m==1)?ff2_b:(m==2)?ta_b:tb_b;
  float w[H_];                                // W_top[:,n] in VGPRs
#pragma unroll
  for (int k = 0; k < H_; ++k) w[k] = wmat[k*H_ + j];
  const float bias_n = bvec[j];

  // hoist per-thread constants
  float gi=0.f, bi=0.f, gi2=0.f, bi2=0.f, pb=0.f, gp=0.f, bp=0.f;
  if (tid < 64) { gi = g_in[tid]; bi = b_in[tid];
                  if (tid < 3) { gi2 = g_in[64+tid]; bi2 = b_in[64+tid]; } }
  if (tid < H_) { pb = proj_b[tid]; gp = g_p[tid]; bp = b_p[tid]; }
  __syncthreads();

  const int ntok = TOK_/256;                  // 1024 tokens per WG
  const int tok0 = blockIdx.x * ntok;
  for (int it = 0; it < ntok; ++it) {
    const int token = tok0 + it;
    // ---- LN over D=67 (wave 0 only) ----
    if (tid < 64) {
      const float* xr = x + (size_t)token*D_;
      float a  = xr[tid];
      float a2 = (tid < 3) ? xr[64+tid] : 0.f;
      float s = a + a2, q = a*a + a2*a2;
#pragma unroll
      for (int off = 32; off; off >>= 1) { s += __shfl_xor(s, off); q += __shfl_xor(q, off); }
      float mu   = s * (1.0f/D_);
      float rstd = rsqrtf(q * (1.0f/D_) - mu*mu + 1e-5f);
      xn[tid] = (a - mu)*rstd*gi + bi;
      if (tid < 3) xn[64+tid] = (a2 - mu)*rstd*gi2 + bi2;
    }
    __syncthreads();
    // ---- proj + LN stats over 128 (waves 0-1) ----
    float pval = 0.f;
    if (tid < H_) {
      float acc0 = pb, acc1 = 0.f;
      for (int d = 0; d+1 < D_; d += 2) {
        acc0 += xn[d]   * pw[d*H_     + tid];
        acc1 += xn[d+1] * pw[(d+1)*H_ + tid];
      }
      acc0 += xn[D_-1] * pw[(D_-1)*H_ + tid];   // D_ odd
      pval = acc0 + acc1;
      float s = pval, q = pval*pval;
#pragma unroll
      for (int off = 32; off; off >>= 1) { s += __shfl_xor(s, off); q += __shfl_xor(q, off); }
      if ((tid & 63) == 0) { red[tid>>6] = s; red[2+(tid>>6)] = q; }
    }
    __syncthreads();
    if (tid < H_) {
      float s = red[0]+red[1], q = red[2]+red[3];
      float mu   = s * (1.0f/H_);
      float rstd = rsqrtf(q * (1.0f/H_) - mu*mu + 1e-5f);
      float v = (pval - mu)*rstd*gp + bp;
      feat[tid] = v * sigm(v);                  // SiLU
    }
    __syncthreads();
    // ---- z_x row: all 512 threads, 1 column each ----
    {
      float a0 = bias_n, a1 = 0.f, a2 = 0.f, a3 = 0.f;
      const float4* f4 = (const float4*)feat;
#pragma unroll
      for (int kk = 0; kk < H_/4; ++kk) {
        float4 h4 = f4[kk];                     // LDS broadcast b128
        a0 += h4.x * w[4*kk+0];
        a1 += h4.y * w[4*kk+1];
        a2 += h4.z * w[4*kk+2];
        a3 += h4.w * w[4*kk+3];
      }
      zx[(size_t)token*N_ + n] = (zfp)((a0+a1)+(a2+a3));
    }
    __syncthreads();
  }
}

// ---------------------------------------------------------------------------
// Stage B (sequential scan): 64 WGs (one per batch) x 512 threads.
// Per step: pre[n] = z_x[b,t,n] + h @ W_bot[:,n]; nonlinear combine -> h_new;
// logit fused (head_w dot) so seq is never materialized.
// W_bot column (128 f32) per thread in VGPRs; h broadcast from LDS.
// ---------------------------------------------------------------------------
__global__ __launch_bounds__(512, 2)
void scan_k(const zfp* __restrict__ zx, const float* __restrict__ dt,
            const float* __restrict__ ff1_w, const float* __restrict__ ff2_w,
            const float* __restrict__ ta_w, const float* __restrict__ tb_w,
            const float* __restrict__ head_w, const float* __restrict__ head_b,
            float* __restrict__ out)
{
  __shared__ __align__(16) float hlds[H_];
  __shared__ float spre[N_];
  __shared__ float prod[H_];
  const int tid = threadIdx.x;
  const int b   = blockIdx.x;
  const int m = tid >> 7, j = tid & 127;
  const float* wmat = (m==0)?ff1_w:(m==1)?ff2_w:(m==2)?ta_w:tb_w;
  float w[H_];                                 // W_bot[:,n] in VGPRs
#pragma unroll
  for (int k = 0; k < H_; ++k) w[k] = wmat[(H_+k)*H_ + j];
  float hw = 0.f;
  if (tid < H_) hw = head_w[tid];
  const float hb = head_b[0];
  if (tid < H_) hlds[tid] = 0.f;
  __syncthreads();

  const zfp*   zrow  = zx  + (size_t)b*T_*N_;
  const float* dtrow = dt  + (size_t)b*T_;
  float*       orow  = out + (size_t)b*T_;

  for (int t = 0; t < T_; ++t) {
    float zval = (float)zrow[(size_t)t*N_ + tid];   // issue early
    float dtv  = dtrow[t];                          // uniform, issue early
    float a0 = 0.f, a1 = 0.f, a2 = 0.f, a3 = 0.f;
    const float4* h4p = (const float4*)hlds;
#pragma unroll
    for (int kk = 0; kk < H_/4; ++kk) {
      float4 h4 = h4p[kk];                          // LDS broadcast b128
      a0 += h4.x * w[4*kk+0];
      a1 += h4.y * w[4*kk+1];
      a2 += h4.z * w[4*kk+2];
      a3 += h4.w * w[4*kk+3];
    }
    spre[tid] = ((a0+a1)+(a2+a3)) + zval;
    __syncthreads();
    if (tid < H_) {
      float f1 = tanh_(spre[j]);
      float f2 = tanh_(spre[H_ + j]);
      float g  = sigm(spre[2*H_ + j] * (dtv*10.0f) + spre[3*H_ + j]);
      float hn = f1 + g*(f2 - f1);
      hlds[j] = hn;
      prod[j] = hn * hw;
    }
    __syncthreads();
    if (tid < 64) {                                 // fused head: dot(h, head_w)
      float s = prod[tid] + prod[64+tid];
#pragma unroll
      for (int off = 32; off; off >>= 1) s += __shfl_xor(s, off);
      if (tid == 0) orow[t] = s + hb;
    }
  }
}

extern "C" void kernel_launch(void* const* d_in, const int* in_sizes, int n_in,
                              void* d_out, int out_size, void* d_ws, size_t ws_size,
                              hipStream_t stream)
{
  const float* x       = (const float*)d_in[0];
  const float* dt      = (const float*)d_in[1];
  const float* ln_in_g = (const float*)d_in[2];
  const float* ln_in_b = (const float*)d_in[3];
  const float* proj_w  = (const float*)d_in[4];
  const float* proj_b  = (const float*)d_in[5];
  const float* ln_p_g  = (const float*)d_in[6];
  const float* ln_p_b  = (const float*)d_in[7];
  const float* ff1_w   = (const float*)d_in[8];
  const float* ff1_b   = (const float*)d_in[9];
  const float* ff2_w   = (const float*)d_in[10];
  const float* ff2_b   = (const float*)d_in[11];
  const float* ta_w    = (const float*)d_in[12];
  const float* ta_b    = (const float*)d_in[13];
  const float* tb_w    = (const float*)d_in[14];
  const float* tb_b    = (const float*)d_in[15];
  const float* head_w  = (const float*)d_in[16];
  const float* head_b  = (const float*)d_in[17];

  zfp*   zx  = (zfp*)d_ws;      // TOK_*512*2 B = 256 MiB
  float* out = (float*)d_out;   // [B,T,1] fp32

  stage_a<<<dim3(256), dim3(512), 0, stream>>>(
      x, ln_in_g, ln_in_b, proj_w, proj_b, ln_p_g, ln_p_b,
      ff1_w, ff1_b, ff2_w, ff2_b, ta_w, ta_b, tb_w, tb_b, zx);

  scan_k<<<dim3(B_), dim3(512), 0, stream>>>(
      zx, dt, ff1_w, ff2_w, ta_w, tb_w, head_w, head_b, out);
}

// Round 2
// 5596.878 us; speedup vs baseline: 1.6427x; 1.6427x over previous
//
#include <hip/hip_runtime.h>
#include <cstdint>

#define Bb 64
#define Tt 4096
#define Dd 67
#define Hh 128

typedef _Float16 f16;
typedef _Float16 half8 __attribute__((ext_vector_type(8)));
typedef float f32x4 __attribute__((ext_vector_type(4)));

#define MFMA16(A,B,C) __builtin_amdgcn_mfma_f32_16x16x32_f16((A),(B),(C),0,0,0)

__device__ __forceinline__ float sigm(float x){ return 1.0f/(1.0f+__expf(-x)); }
__device__ __forceinline__ float tanh_(float x){ return 1.0f - 2.0f/(__expf(2.0f*x)+1.0f); }

union U2 { uint2 u; f16 h[4]; };

__device__ __forceinline__ void red2(float& s, float& q){
#pragma unroll
  for (int off = 32; off; off >>= 1){ s += __shfl_xor(s, off); q += __shfl_xor(q, off); }
}

// ---------------------------------------------------------------------------
// Stage A: per 16-token tile: LN(67) -> MFMA GEMM1 (proj 67->128, K padded 96)
//   -> LN(128)+SiLU -> MFMA GEMM2 (feat@W_top -> z[512]) -> z fp16 to d_ws in
//   the scan's [gb][t][m][n] layout. Transposed MFMA: weights = A (VGPR-resident),
//   activations = B (one ds_read_b128 per K-chunk). 256 WGs x 512 thr, 64 iters.
// ---------------------------------------------------------------------------
__global__ __launch_bounds__(512, 2)
void stage_a(const float* __restrict__ x,
             const float* __restrict__ g_in, const float* __restrict__ b_in,
             const float* __restrict__ proj_w, const float* __restrict__ proj_b,
             const float* __restrict__ g_p, const float* __restrict__ b_p,
             const float* __restrict__ w_ff1, const float* __restrict__ bi_ff1,
             const float* __restrict__ w_ff2, const float* __restrict__ bi_ff2,
             const float* __restrict__ w_ta,  const float* __restrict__ bi_ta,
             const float* __restrict__ w_tb,  const float* __restrict__ bi_tb,
             f16* __restrict__ zx)
{
  // pad strides chosen: 16B-aligned AND <=2-way bank aliasing (free per m136)
  __shared__ __align__(16) f16   xn_s[16*104];   // [tok][k96 pad 104]
  __shared__ __align__(16) float fpre_s[16*132]; // [tok][h128 pad 132] f32
  __shared__ __align__(16) f16   feat_s[16*136]; // [tok][k128 pad 136]

  const int tid  = threadIdx.x;
  const int wv   = tid >> 6;
  const int lane = tid & 63;
  const int q    = lane >> 4;
  const int l16  = lane & 15;
  const int jq   = 16*wv + 4*q;      // row base within this wave's M-tile

  const float* Wg[4] = { w_ff1, w_ff2, w_ta, w_tb };
  const float* Bg[4] = { bi_ff1, bi_ff2, bi_ta, bi_tb };

  // ---- one-time preloads ----
  // GEMM1 A = proj_w^T : A[h=16wv+l16][k], K padded to 96 with zeros
  half8 aW1[3];
#pragma unroll
  for (int c = 0; c < 3; ++c)
#pragma unroll
    for (int i = 0; i < 8; ++i){
      int k = 32*c + 8*q + i;
      aW1[c][i] = (k < Dd) ? (f16)proj_w[k*Hh + (16*wv + l16)] : (f16)0.f;
    }
  // GEMM2 A = W_top^T per gate: A[n = g*128 + 16wv + l16][k], k in 0..127
  half8 aW2[4][4];
  f32x4 bias2[4];
#pragma unroll
  for (int g = 0; g < 4; ++g){
    const float* wp = Wg[g];
    const int jc = 16*wv + l16;
#pragma unroll
    for (int c = 0; c < 4; ++c)
#pragma unroll
      for (int i = 0; i < 8; ++i){
        int k = 32*c + 8*q + i;
        aW2[g][c][i] = (f16)wp[k*Hh + jc];
      }
    const float* bp = Bg[g];
    bias2[g] = *(const f32x4*)(bp + jq);     // bias for acc regs r=0..3
  }
  // LN consts
  const float gi0 = g_in[lane], bi0 = b_in[lane];
  const float gi1 = (lane < 3) ? g_in[64+lane] : 0.f;
  const float bi1 = (lane < 3) ? b_in[64+lane] : 0.f;
  const float gp0 = g_p[lane],  bp0 = b_p[lane];
  const float gp1 = g_p[64+lane], bp1 = b_p[64+lane];
  const float pb0 = proj_b[lane], pb1 = proj_b[64+lane];

  // zero xn pad cols (67..103) once; token writes only touch k<67
  for (int idx = tid; idx < 16*104; idx += 512)
    if ((idx % 104) >= Dd) xn_s[idx] = (f16)0.f;
  __syncthreads();

  const int wg   = blockIdx.x;
  const int b    = wg >> 2;                  // 4 WGs per batch-row
  const int t0wg = (wg & 3) * 1024;
  const size_t zbase = (size_t)(b >> 3) * ((size_t)Tt * 4096) + (size_t)(b & 7) * 512;

  for (int it = 0; it < 64; ++it){
    const int tl0 = t0wg + it*16;
    // ---- LN over 67: each wave does 2 tokens ----
#pragma unroll
    for (int hf = 0; hf < 2; ++hf){
      const int ts = wv + 8*hf;
      const float* xr = x + (size_t)(b*Tt + tl0 + ts) * Dd;
      float v0 = xr[lane];
      float v1 = (lane < 3) ? xr[64+lane] : 0.f;
      float s = v0 + v1, qq = v0*v0 + v1*v1;
      red2(s, qq);
      float mu = s * (1.0f/Dd);
      float rstd = rsqrtf(qq * (1.0f/Dd) - mu*mu + 1e-5f);
      xn_s[ts*104 + lane] = (f16)((v0 - mu)*rstd*gi0 + bi0);
      if (lane < 3) xn_s[ts*104 + 64 + lane] = (f16)((v1 - mu)*rstd*gi1 + bi1);
    }
    __syncthreads();
    // ---- GEMM1: fpre[h][tok] = proj_w^T @ xn^T ----
    {
      f32x4 acc = {0.f, 0.f, 0.f, 0.f};
#pragma unroll
      for (int c = 0; c < 3; ++c){
        half8 bf = *(const half8*)(xn_s + l16*104 + 32*c + 8*q);
        acc = MFMA16(aW1[c], bf, acc);
      }
      *(f32x4*)(fpre_s + l16*132 + jq) = acc;   // rows h=jq+r, col tok=l16
    }
    __syncthreads();
    // ---- LN over 128 + SiLU: each wave does 2 tokens ----
#pragma unroll
    for (int hf = 0; hf < 2; ++hf){
      const int ts = wv + 8*hf;
      float v0 = fpre_s[ts*132 + lane]      + pb0;
      float v1 = fpre_s[ts*132 + 64 + lane] + pb1;
      float s = v0 + v1, qq = v0*v0 + v1*v1;
      red2(s, qq);
      float mu = s * (1.0f/Hh);
      float rstd = rsqrtf(qq * (1.0f/Hh) - mu*mu + 1e-5f);
      float f0 = (v0 - mu)*rstd*gp0 + bp0;  f0 *= sigm(f0);
      float f1 = (v1 - mu)*rstd*gp1 + bp1;  f1 *= sigm(f1);
      feat_s[ts*136 + lane]      = (f16)f0;
      feat_s[ts*136 + 64 + lane] = (f16)f1;
    }
    __syncthreads();
    // ---- GEMM2: z[n][tok] = W_top^T @ feat^T + bias; store fp16 b64 ----
    {
      half8 bf2[4];
#pragma unroll
      for (int c = 0; c < 4; ++c)
        bf2[c] = *(const half8*)(feat_s + l16*136 + 32*c + 8*q);
      const size_t trow = zbase + (size_t)(tl0 + l16) * 4096;
#pragma unroll
      for (int g = 0; g < 4; ++g){
        f32x4 acc = bias2[g];
#pragma unroll
        for (int c = 0; c < 4; ++c)
          acc = MFMA16(aW2[g][c], bf2[c], acc);
        U2 u;
#pragma unroll
        for (int r = 0; r < 4; ++r) u.h[r] = (f16)acc[r];
        *(uint2*)(zx + trow + g*128 + jq) = u.u;
      }
    }
    __syncthreads();
  }
}

// ---------------------------------------------------------------------------
// Scan: 8 WGs x 8 batches x 512 thr. Transposed MFMA per step:
//   pre^T[n][m] = W_bot^T (A, VGPR) @ h^T (B, 4 ds_read_b128) + z (prefetched).
// Gate tiles land elementwise in-lane; h_new -> 1 ds_write_b64 into parity
// double-buffered LDS; 1 barrier/step; head fused (2 shuffles + LDS partials).
// Columns m>=8 compute isolated garbage (matmul cols don't mix) — never stored.
// ---------------------------------------------------------------------------
__global__ __launch_bounds__(512, 2)
void scan_k(const f16* __restrict__ zx, const float* __restrict__ dt,
            const float* __restrict__ w_ff1, const float* __restrict__ w_ff2,
            const float* __restrict__ w_ta,  const float* __restrict__ w_tb,
            const float* __restrict__ head_w, const float* __restrict__ head_b,
            float* __restrict__ out)
{
  __shared__ __align__(16) f16 h_s[2][16*136];  // [parity][m][k128 pad 136]
  __shared__ float dtb[2][8];
  __shared__ float hp[2][8][16];

  const int tid  = threadIdx.x;
  const int wv   = tid >> 6;
  const int lane = tid & 63;
  const int q    = lane >> 4;
  const int l16  = lane & 15;
  const int jq   = 16*wv + 4*q;                 // this lane's 4 h-cols j=jq+r
  const int b0   = blockIdx.x * 8;

  const float* Wg[4] = { w_ff1, w_ff2, w_ta, w_tb };

  // A = W_bot^T per gate: A[n = g*128 + 16wv + l16][k], k rows 128..255
  half8 aW[4][4];
#pragma unroll
  for (int g = 0; g < 4; ++g){
    const float* wp = Wg[g];
    const int jc = 16*wv + l16;
#pragma unroll
    for (int c = 0; c < 4; ++c)
#pragma unroll
      for (int i = 0; i < 8; ++i){
        int k = 128 + 32*c + 8*q + i;
        aW[g][c][i] = (f16)wp[k*Hh + jc];
      }
  }
  const f32x4 hwv = *(const f32x4*)(head_w + jq);
  const float hb = head_b[0];

  // zero h state (both parities; rows 8..15 stay zero -> clean B cols)
  {
    f16* hz = &h_s[0][0];
    for (int idx = tid; idx < 2*16*136; idx += 512) hz[idx] = (f16)0.f;
  }
  if (tid < 8) dtb[0][tid] = dt[(size_t)(b0 + tid)*Tt + 0] * 10.f;
  __syncthreads();

  const size_t zb = (size_t)blockIdx.x * ((size_t)Tt * 4096);
  const int mloc = l16;
  const bool zok = mloc < 8;

  // prefetch z for t=0
  uint2 zn[4];
#pragma unroll
  for (int g = 0; g < 4; ++g){
    zn[g] = make_uint2(0u, 0u);
    if (zok) zn[g] = *(const uint2*)(zx + zb + (size_t)mloc*512 + g*128 + jq);
  }

  for (int t = 0; t < Tt; ++t){
    const int p = t & 1;
    // B-frags: h^T[k][m=l16], 8 contiguous k per chunk
    half8 bf[4];
#pragma unroll
    for (int c = 0; c < 4; ++c)
      bf[c] = *(const half8*)(&h_s[p][l16*136 + 32*c + 8*q]);

    uint2 zc[4];
#pragma unroll
    for (int g = 0; g < 4; ++g) zc[g] = zn[g];
    if (t + 1 < Tt && zok){
      const size_t za = zb + (size_t)(t+1)*4096 + (size_t)mloc*512;
#pragma unroll
      for (int g = 0; g < 4; ++g)
        zn[g] = *(const uint2*)(zx + za + g*128 + jq);
    }
    const float dtt = dtb[p][mloc & 7];

    f32x4 accs[4];
#pragma unroll
    for (int g = 0; g < 4; ++g){
      U2 u; u.u = zc[g];
      f32x4 a = { (float)u.h[0], (float)u.h[1], (float)u.h[2], (float)u.h[3] };
#pragma unroll
      for (int c = 0; c < 4; ++c)
        a = MFMA16(aW[g][c], bf[c], a);
      accs[g] = a;
    }
    // elementwise CfC cell (rows jq+r, col m) — all in-register
    U2 hu;
    float hpart = 0.f;
#pragma unroll
    for (int r = 0; r < 4; ++r){
      float f1 = tanh_(accs[0][r]);
      float f2 = tanh_(accs[1][r]);
      float gg = sigm(accs[2][r]*dtt + accs[3][r]);
      float hn = f1 + gg*(f2 - f1);
      hu.h[r] = (f16)hn;
      hpart += hn * hwv[r];
    }
    *(uint2*)(&h_s[p^1][l16*136 + jq]) = hu.u;   // one b64 write

    // head partial: sum over quads -> every lane holds batch-m total for its j-slice
    hpart += __shfl_xor(hpart, 16);
    hpart += __shfl_xor(hpart, 32);
    if (lane < 16) hp[p][wv][l16] = hpart;

    if (tid < 8) dtb[p^1][tid] = dt[(size_t)(b0 + tid)*Tt + ((t+1 < Tt) ? t+1 : t)] * 10.f;
    __syncthreads();

    if (tid < 8){
      float s = hb;
#pragma unroll
      for (int w2 = 0; w2 < 8; ++w2) s += hp[p][w2][tid];
      out[(size_t)(b0 + tid)*Tt + t] = s;
    }
  }
}

extern "C" void kernel_launch(void* const* d_in, const int* in_sizes, int n_in,
                              void* d_out, int out_size, void* d_ws, size_t ws_size,
                              hipStream_t stream)
{
  const float* x       = (const float*)d_in[0];
  const float* dt      = (const float*)d_in[1];
  const float* ln_in_g = (const float*)d_in[2];
  const float* ln_in_b = (const float*)d_in[3];
  const float* proj_w  = (const float*)d_in[4];
  const float* proj_b  = (const float*)d_in[5];
  const float* ln_p_g  = (const float*)d_in[6];
  const float* ln_p_b  = (const float*)d_in[7];
  const float* ff1_w   = (const float*)d_in[8];
  const float* ff1_b   = (const float*)d_in[9];
  const float* ff2_w   = (const float*)d_in[10];
  const float* ff2_b   = (const float*)d_in[11];
  const float* ta_w    = (const float*)d_in[12];
  const float* ta_b    = (const float*)d_in[13];
  const float* tb_w    = (const float*)d_in[14];
  const float* tb_b    = (const float*)d_in[15];
  const float* head_w  = (const float*)d_in[16];
  const float* head_b  = (const float*)d_in[17];

  f16*   zx  = (f16*)d_ws;      // 8 slabs x [4096 t][8 m][512 n] fp16 = 256 MiB
  float* out = (float*)d_out;

  stage_a<<<dim3(256), dim3(512), 0, stream>>>(
      x, ln_in_g, ln_in_b, proj_w, proj_b, ln_p_g, ln_p_b,
      ff1_w, ff1_b, ff2_w, ff2_b, ta_w, ta_b, tb_w, tb_b, zx);

  scan_k<<<dim3(8), dim3(512), 0, stream>>>(
      zx, dt, ff1_w, ff2_w, ta_w, tb_w, head_w, head_b, out);
}

// Round 3
// 3489.981 us; speedup vs baseline: 2.6344x; 1.6037x over previous
//
#include <hip/hip_runtime.h>
#include <cstdint>

#define Bb 64
#define Tt 4096
#define Dd 67
#define Hh 128

typedef _Float16 f16;
typedef _Float16 half8 __attribute__((ext_vector_type(8)));
typedef float f32x4 __attribute__((ext_vector_type(4)));

#define MFMA16(A,B,C) __builtin_amdgcn_mfma_f32_16x16x32_f16((A),(B),(C),0,0,0)

static __device__ __forceinline__ float fast_rcp(float x){ return __builtin_amdgcn_rcpf(x); }
static __device__ __forceinline__ float fast_ex2(float x){ return __builtin_amdgcn_exp2f(x); }
#define L2E  1.442695041f
#define L2E2 2.885390082f

union U2 { uint2 u; f16 h[4]; };

__device__ __forceinline__ void red2(float& s, float& q){
#pragma unroll
  for (int off = 32; off; off >>= 1){ s += __shfl_xor(s, off); q += __shfl_xor(q, off); }
}

// ---------------------------------------------------------------------------
// Stage A: per 16-token tile: LN(67) -> MFMA GEMM1 (proj) -> LN(128)+SiLU ->
// MFMA GEMM2 -> z fp16 to d_ws in [b][t][n] layout (scan-friendly).
// Weights = A operand (VGPR-resident), activations = B operand.
// ---------------------------------------------------------------------------
__global__ __launch_bounds__(512, 2)
void stage_a(const float* __restrict__ x,
             const float* __restrict__ g_in, const float* __restrict__ b_in,
             const float* __restrict__ proj_w, const float* __restrict__ proj_b,
             const float* __restrict__ g_p, const float* __restrict__ b_p,
             const float* __restrict__ w_ff1, const float* __restrict__ bi_ff1,
             const float* __restrict__ w_ff2, const float* __restrict__ bi_ff2,
             const float* __restrict__ w_ta,  const float* __restrict__ bi_ta,
             const float* __restrict__ w_tb,  const float* __restrict__ bi_tb,
             f16* __restrict__ zx)
{
  __shared__ __align__(16) f16   xn_s[16*104];   // [tok][k96 pad 104]
  __shared__ __align__(16) float fpre_s[16*132]; // [tok][h128 pad 132]
  __shared__ __align__(16) f16   feat_s[16*136]; // [tok][k128 pad 136]

  const int tid  = threadIdx.x;
  const int wv   = tid >> 6;
  const int lane = tid & 63;
  const int q    = lane >> 4;
  const int l16  = lane & 15;
  const int jq   = 16*wv + 4*q;

  const float* Wg[4] = { w_ff1, w_ff2, w_ta, w_tb };
  const float* Bg[4] = { bi_ff1, bi_ff2, bi_ta, bi_tb };

  // GEMM1 A = proj_w^T, K padded to 96 with zeros
  half8 aW1[3];
#pragma unroll
  for (int c = 0; c < 3; ++c)
#pragma unroll
    for (int i = 0; i < 8; ++i){
      int k = 32*c + 8*q + i;
      aW1[c][i] = (k < Dd) ? (f16)proj_w[k*Hh + (16*wv + l16)] : (f16)0.f;
    }
  // GEMM2 A = W_top^T per gate
  half8 aW2[4][4];
  f32x4 bias2[4];
#pragma unroll
  for (int g = 0; g < 4; ++g){
    const float* wp = Wg[g];
    const int jc = 16*wv + l16;
#pragma unroll
    for (int c = 0; c < 4; ++c)
#pragma unroll
      for (int i = 0; i < 8; ++i){
        int k = 32*c + 8*q + i;
        aW2[g][c][i] = (f16)wp[k*Hh + jc];
      }
    bias2[g] = *(const f32x4*)(Bg[g] + jq);
  }
  const float gi0 = g_in[lane], bi0 = b_in[lane];
  const float gi1 = (lane < 3) ? g_in[64+lane] : 0.f;
  const float bi1 = (lane < 3) ? b_in[64+lane] : 0.f;
  const float gp0 = g_p[lane],  bp0 = b_p[lane];
  const float gp1 = g_p[64+lane], bp1 = b_p[64+lane];
  const float pb0 = proj_b[lane], pb1 = proj_b[64+lane];

  for (int idx = tid; idx < 16*104; idx += 512)
    if ((idx % 104) >= Dd) xn_s[idx] = (f16)0.f;
  __syncthreads();

  const int wg   = blockIdx.x;
  const int b    = wg >> 2;
  const int t0wg = (wg & 3) * 1024;

  for (int it = 0; it < 64; ++it){
    const int tl0 = t0wg + it*16;
#pragma unroll
    for (int hf = 0; hf < 2; ++hf){
      const int ts = wv + 8*hf;
      const float* xr = x + (size_t)(b*Tt + tl0 + ts) * Dd;
      float v0 = xr[lane];
      float v1 = (lane < 3) ? xr[64+lane] : 0.f;
      float s = v0 + v1, qq = v0*v0 + v1*v1;
      red2(s, qq);
      float mu = s * (1.0f/Dd);
      float rstd = rsqrtf(qq * (1.0f/Dd) - mu*mu + 1e-5f);
      xn_s[ts*104 + lane] = (f16)((v0 - mu)*rstd*gi0 + bi0);
      if (lane < 3) xn_s[ts*104 + 64 + lane] = (f16)((v1 - mu)*rstd*gi1 + bi1);
    }
    __syncthreads();
    {
      f32x4 acc = {0.f, 0.f, 0.f, 0.f};
#pragma unroll
      for (int c = 0; c < 3; ++c){
        half8 bf = *(const half8*)(xn_s + l16*104 + 32*c + 8*q);
        acc = MFMA16(aW1[c], bf, acc);
      }
      *(f32x4*)(fpre_s + l16*132 + jq) = acc;
    }
    __syncthreads();
#pragma unroll
    for (int hf = 0; hf < 2; ++hf){
      const int ts = wv + 8*hf;
      float v0 = fpre_s[ts*132 + lane]      + pb0;
      float v1 = fpre_s[ts*132 + 64 + lane] + pb1;
      float s = v0 + v1, qq = v0*v0 + v1*v1;
      red2(s, qq);
      float mu = s * (1.0f/Hh);
      float rstd = rsqrtf(qq * (1.0f/Hh) - mu*mu + 1e-5f);
      float f0 = (v0 - mu)*rstd*gp0 + bp0;
      float f1 = (v1 - mu)*rstd*gp1 + bp1;
      f0 *= fast_rcp(1.0f + fast_ex2(-L2E*f0));   // SiLU
      f1 *= fast_rcp(1.0f + fast_ex2(-L2E*f1));
      feat_s[ts*136 + lane]      = (f16)f0;
      feat_s[ts*136 + 64 + lane] = (f16)f1;
    }
    __syncthreads();
    {
      half8 bf2[4];
#pragma unroll
      for (int c = 0; c < 4; ++c)
        bf2[c] = *(const half8*)(feat_s + l16*136 + 32*c + 8*q);
      const size_t trow = (size_t)(b*Tt + tl0 + l16) * 512;
#pragma unroll
      for (int g = 0; g < 4; ++g){
        f32x4 acc = bias2[g];
#pragma unroll
        for (int c = 0; c < 4; ++c)
          acc = MFMA16(aW2[g][c], bf2[c], acc);
        U2 u;
#pragma unroll
        for (int r = 0; r < 4; ++r) u.h[r] = (f16)acc[r];
        *(uint2*)(zx + trow + g*128 + jq) = u.u;
      }
    }
    __syncthreads();
  }
}

// ---------------------------------------------------------------------------
// Scan v3: 64 WGs x 1 batch x 512 thr. h = one 256B LDS row (parity dbuf);
// B-frag reads are same-address broadcasts (conflict-free). Fast exp2/rcp
// nonlinearity (no IEEE divides). z prefetched 2 steps ahead in registers.
// dt*10 staged to LDS once. Head dot reduced one step late (off crit path).
// ---------------------------------------------------------------------------
__global__ __launch_bounds__(512, 2)
void scan_k(const f16* __restrict__ zx, const float* __restrict__ dt,
            const float* __restrict__ w_ff1, const float* __restrict__ w_ff2,
            const float* __restrict__ w_ta,  const float* __restrict__ w_tb,
            const float* __restrict__ head_w, const float* __restrict__ head_b,
            float* __restrict__ out)
{
  __shared__ __align__(16) f16 h_s[2][Hh];   // 2 x 256B
  __shared__ float dts[Tt];                  // 16 KB
  __shared__ float hp[2][8];

  const int tid  = threadIdx.x;
  const int wv   = tid >> 6;
  const int lane = tid & 63;
  const int q    = lane >> 4;
  const int l16  = lane & 15;
  const int jq   = 16*wv + 4*q;
  const int b    = blockIdx.x;

  const float* Wg[4] = { w_ff1, w_ff2, w_ta, w_tb };
  half8 aW[4][4];                             // W_bot^T (k rows 128..255)
#pragma unroll
  for (int g = 0; g < 4; ++g){
    const float* wp = Wg[g];
    const int jc = 16*wv + l16;
#pragma unroll
    for (int c = 0; c < 4; ++c)
#pragma unroll
      for (int i = 0; i < 8; ++i)
        aW[g][c][i] = (f16)wp[(128 + 32*c + 8*q + i)*Hh + jc];
  }
  const f32x4 hwv = *(const f32x4*)(head_w + jq);
  const float hb = head_b[0];

  for (int i = tid; i < Tt; i += 512) dts[i] = dt[(size_t)b*Tt + i] * 10.0f;
  if (tid < Hh){ h_s[0][tid] = (f16)0.f; h_s[1][tid] = (f16)0.f; }
  __syncthreads();

  const f16* zrow = zx + (size_t)b*Tt*512 + jq;   // per-lane base; +g*128 imm
  uint2 zA[4], zB[4];
#pragma unroll
  for (int g = 0; g < 4; ++g) zA[g] = *(const uint2*)(zrow + g*128);
#pragma unroll
  for (int g = 0; g < 4; ++g) zB[g] = *(const uint2*)(zrow + 512 + g*128);
  const f16* zp = zrow + 1024;                    // points at t=2

  for (int tt = 0; tt < Tt; tt += 2){
    // ================= even half: t = tt, read h_s[0] -> write h_s[1] ======
    {
      const float dtt = dts[tt];
      half8 bf[4];
#pragma unroll
      for (int c = 0; c < 4; ++c)
        bf[c] = *(const half8*)(&h_s[0][32*c + 8*q]);
      f32x4 accs[4];
#pragma unroll
      for (int g = 0; g < 4; ++g){
        U2 u; u.u = zA[g];
        f32x4 a = { (float)u.h[0], (float)u.h[1], (float)u.h[2], (float)u.h[3] };
#pragma unroll
        for (int c = 0; c < 4; ++c)
          a = MFMA16(aW[g][c], bf[c], a);
        accs[g] = a;
      }
      // prefetch z for t+2
      {
        const f16* ps = (tt + 2 < Tt) ? zp : zrow;
#pragma unroll
        for (int g = 0; g < 4; ++g) zA[g] = *(const uint2*)(ps + g*128);
      }
      // emit out[t-1] (wave 0; partials of previous odd step in hp[1])
      if (tt > 0 && tid < 8){
        float s = hp[1][tid];
        s += __shfl_xor(s, 1); s += __shfl_xor(s, 2); s += __shfl_xor(s, 4);
        if (tid == 0) out[(size_t)b*Tt + (tt-1)] = s + hb;
      }
      // CfC cell
      U2 hu; float hpart = 0.f;
#pragma unroll
      for (int r = 0; r < 4; ++r){
        float u_ = fast_rcp(fast_ex2(L2E2*accs[0][r]) + 1.0f);   // (1-tanh)/2
        float v_ = fast_rcp(fast_ex2(L2E2*accs[1][r]) + 1.0f);
        float g_ = fast_rcp(fast_ex2(-L2E*(accs[2][r]*dtt + accs[3][r])) + 1.0f);
        float hn = 1.0f - 2.0f*(u_ - g_*(u_ - v_));
        hu.h[r] = (f16)hn;
        hpart += hn * hwv[r];
      }
      if (l16 == 0) *(uint2*)(&h_s[1][jq]) = hu.u;
      hpart += __shfl_xor(hpart, 16);
      hpart += __shfl_xor(hpart, 32);
      if (lane == 0) hp[0][wv] = hpart;
      __syncthreads();
    }
    // ================= odd half: t = tt+1, read h_s[1] -> write h_s[0] =====
    {
      const float dtt = dts[tt+1];
      half8 bf[4];
#pragma unroll
      for (int c = 0; c < 4; ++c)
        bf[c] = *(const half8*)(&h_s[1][32*c + 8*q]);
      f32x4 accs[4];
#pragma unroll
      for (int g = 0; g < 4; ++g){
        U2 u; u.u = zB[g];
        f32x4 a = { (float)u.h[0], (float)u.h[1], (float)u.h[2], (float)u.h[3] };
#pragma unroll
        for (int c = 0; c < 4; ++c)
          a = MFMA16(aW[g][c], bf[c], a);
        accs[g] = a;
      }
      // prefetch z for t+3
      {
        const f16* ps = (tt + 3 < Tt) ? zp + 512 : zrow;
#pragma unroll
        for (int g = 0; g < 4; ++g) zB[g] = *(const uint2*)(ps + g*128);
      }
      // emit out[tt] (wave 0; partials in hp[0])
      if (tid < 8){
        float s = hp[0][tid];
        s += __shfl_xor(s, 1); s += __shfl_xor(s, 2); s += __shfl_xor(s, 4);
        if (tid == 0) out[(size_t)b*Tt + tt] = s + hb;
      }
      U2 hu; float hpart = 0.f;
#pragma unroll
      for (int r = 0; r < 4; ++r){
        float u_ = fast_rcp(fast_ex2(L2E2*accs[0][r]) + 1.0f);
        float v_ = fast_rcp(fast_ex2(L2E2*accs[1][r]) + 1.0f);
        float g_ = fast_rcp(fast_ex2(-L2E*(accs[2][r]*dtt + accs[3][r])) + 1.0f);
        float hn = 1.0f - 2.0f*(u_ - g_*(u_ - v_));
        hu.h[r] = (f16)hn;
        hpart += hn * hwv[r];
      }
      if (l16 == 0) *(uint2*)(&h_s[0][jq]) = hu.u;
      hpart += __shfl_xor(hpart, 16);
      hpart += __shfl_xor(hpart, 32);
      if (lane == 0) hp[1][wv] = hpart;
      __syncthreads();
    }
    zp += 1024;
  }
  // final out[T-1] from hp[1]
  if (tid < 8){
    float s = hp[1][tid];
    s += __shfl_xor(s, 1); s += __shfl_xor(s, 2); s += __shfl_xor(s, 4);
    if (tid == 0) out[(size_t)b*Tt + (Tt-1)] = s + hb;
  }
}

extern "C" void kernel_launch(void* const* d_in, const int* in_sizes, int n_in,
                              void* d_out, int out_size, void* d_ws, size_t ws_size,
                              hipStream_t stream)
{
  const float* x       = (const float*)d_in[0];
  const float* dt      = (const float*)d_in[1];
  const float* ln_in_g = (const float*)d_in[2];
  const float* ln_in_b = (const float*)d_in[3];
  const float* proj_w  = (const float*)d_in[4];
  const float* proj_b  = (const float*)d_in[5];
  const float* ln_p_g  = (const float*)d_in[6];
  const float* ln_p_b  = (const float*)d_in[7];
  const float* ff1_w   = (const float*)d_in[8];
  const float* ff1_b   = (const float*)d_in[9];
  const float* ff2_w   = (const float*)d_in[10];
  const float* ff2_b   = (const float*)d_in[11];
  const float* ta_w    = (const float*)d_in[12];
  const float* ta_b    = (const float*)d_in[13];
  const float* tb_w    = (const float*)d_in[14];
  const float* tb_b    = (const float*)d_in[15];
  const float* head_w  = (const float*)d_in[16];
  const float* head_b  = (const float*)d_in[17];

  f16*   zx  = (f16*)d_ws;      // [b][t][n] fp16 = 256 MiB
  float* out = (float*)d_out;

  stage_a<<<dim3(256), dim3(512), 0, stream>>>(
      x, ln_in_g, ln_in_b, proj_w, proj_b, ln_p_g, ln_p_b,
      ff1_w, ff1_b, ff2_w, ff2_b, ta_w, ta_b, tb_w, tb_b, zx);

  scan_k<<<dim3(Bb), dim3(512), 0, stream>>>(
      zx, dt, ff1_w, ff2_w, ta_w, tb_w, head_w, head_b, out);
}

// Round 4
// 3098.394 us; speedup vs baseline: 2.9674x; 1.1264x over previous
//
#include <hip/hip_runtime.h>
#include <cstdint>

#define Bb 64
#define Tt 4096
#define Dd 67
#define Hh 128
#define CH 16            // scan z-chunk: 16 steps x 512 n x 2B = 16 KB

typedef _Float16 f16;
typedef _Float16 half8 __attribute__((ext_vector_type(8)));
typedef float f32x4 __attribute__((ext_vector_type(4)));

#define MFMA16(A,B,C) __builtin_amdgcn_mfma_f32_16x16x32_f16((A),(B),(C),0,0,0)

static __device__ __forceinline__ float fast_rcp(float x){ return __builtin_amdgcn_rcpf(x); }
static __device__ __forceinline__ float fast_ex2(float x){ return __builtin_amdgcn_exp2f(x); }
#define L2E  1.442695041f
#define L2E2 2.885390082f

union U2 { uint2 u; f16 h[4]; };

__device__ __forceinline__ void red2(float& s, float& q){
#pragma unroll
  for (int off = 32; off; off >>= 1){ s += __shfl_xor(s, off); q += __shfl_xor(q, off); }
}

// ---------------------------------------------------------------------------
// Stage A (unchanged from R3): LN(67) -> MFMA proj -> LN(128)+SiLU -> MFMA
// GEMM2 -> z fp16 [b][t][n].
// ---------------------------------------------------------------------------
__global__ __launch_bounds__(512, 2)
void stage_a(const float* __restrict__ x,
             const float* __restrict__ g_in, const float* __restrict__ b_in,
             const float* __restrict__ proj_w, const float* __restrict__ proj_b,
             const float* __restrict__ g_p, const float* __restrict__ b_p,
             const float* __restrict__ w_ff1, const float* __restrict__ bi_ff1,
             const float* __restrict__ w_ff2, const float* __restrict__ bi_ff2,
             const float* __restrict__ w_ta,  const float* __restrict__ bi_ta,
             const float* __restrict__ w_tb,  const float* __restrict__ bi_tb,
             f16* __restrict__ zx)
{
  __shared__ __align__(16) f16   xn_s[16*104];
  __shared__ __align__(16) float fpre_s[16*132];
  __shared__ __align__(16) f16   feat_s[16*136];

  const int tid  = threadIdx.x;
  const int wv   = tid >> 6;
  const int lane = tid & 63;
  const int q    = lane >> 4;
  const int l16  = lane & 15;
  const int jq   = 16*wv + 4*q;

  const float* Wg[4] = { w_ff1, w_ff2, w_ta, w_tb };
  const float* Bg[4] = { bi_ff1, bi_ff2, bi_ta, bi_tb };

  half8 aW1[3];
#pragma unroll
  for (int c = 0; c < 3; ++c)
#pragma unroll
    for (int i = 0; i < 8; ++i){
      int k = 32*c + 8*q + i;
      aW1[c][i] = (k < Dd) ? (f16)proj_w[k*Hh + (16*wv + l16)] : (f16)0.f;
    }
  half8 aW2[4][4];
  f32x4 bias2[4];
#pragma unroll
  for (int g = 0; g < 4; ++g){
    const float* wp = Wg[g];
    const int jc = 16*wv + l16;
#pragma unroll
    for (int c = 0; c < 4; ++c)
#pragma unroll
      for (int i = 0; i < 8; ++i){
        int k = 32*c + 8*q + i;
        aW2[g][c][i] = (f16)wp[k*Hh + jc];
      }
    bias2[g] = *(const f32x4*)(Bg[g] + jq);
  }
  const float gi0 = g_in[lane], bi0 = b_in[lane];
  const float gi1 = (lane < 3) ? g_in[64+lane] : 0.f;
  const float bi1 = (lane < 3) ? b_in[64+lane] : 0.f;
  const float gp0 = g_p[lane],  bp0 = b_p[lane];
  const float gp1 = g_p[64+lane], bp1 = b_p[64+lane];
  const float pb0 = proj_b[lane], pb1 = proj_b[64+lane];

  for (int idx = tid; idx < 16*104; idx += 512)
    if ((idx % 104) >= Dd) xn_s[idx] = (f16)0.f;
  __syncthreads();

  const int wg   = blockIdx.x;
  const int b    = wg >> 2;
  const int t0wg = (wg & 3) * 1024;

  for (int it = 0; it < 64; ++it){
    const int tl0 = t0wg + it*16;
#pragma unroll
    for (int hf = 0; hf < 2; ++hf){
      const int ts = wv + 8*hf;
      const float* xr = x + (size_t)(b*Tt + tl0 + ts) * Dd;
      float v0 = xr[lane];
      float v1 = (lane < 3) ? xr[64+lane] : 0.f;
      float s = v0 + v1, qq = v0*v0 + v1*v1;
      red2(s, qq);
      float mu = s * (1.0f/Dd);
      float rstd = rsqrtf(qq * (1.0f/Dd) - mu*mu + 1e-5f);
      xn_s[ts*104 + lane] = (f16)((v0 - mu)*rstd*gi0 + bi0);
      if (lane < 3) xn_s[ts*104 + 64 + lane] = (f16)((v1 - mu)*rstd*gi1 + bi1);
    }
    __syncthreads();
    {
      f32x4 acc = {0.f, 0.f, 0.f, 0.f};
#pragma unroll
      for (int c = 0; c < 3; ++c){
        half8 bf = *(const half8*)(xn_s + l16*104 + 32*c + 8*q);
        acc = MFMA16(aW1[c], bf, acc);
      }
      *(f32x4*)(fpre_s + l16*132 + jq) = acc;
    }
    __syncthreads();
#pragma unroll
    for (int hf = 0; hf < 2; ++hf){
      const int ts = wv + 8*hf;
      float v0 = fpre_s[ts*132 + lane]      + pb0;
      float v1 = fpre_s[ts*132 + 64 + lane] + pb1;
      float s = v0 + v1, qq = v0*v0 + v1*v1;
      red2(s, qq);
      float mu = s * (1.0f/Hh);
      float rstd = rsqrtf(qq * (1.0f/Hh) - mu*mu + 1e-5f);
      float f0 = (v0 - mu)*rstd*gp0 + bp0;
      float f1 = (v1 - mu)*rstd*gp1 + bp1;
      f0 *= fast_rcp(1.0f + fast_ex2(-L2E*f0));
      f1 *= fast_rcp(1.0f + fast_ex2(-L2E*f1));
      feat_s[ts*136 + lane]      = (f16)f0;
      feat_s[ts*136 + 64 + lane] = (f16)f1;
    }
    __syncthreads();
    {
      half8 bf2[4];
#pragma unroll
      for (int c = 0; c < 4; ++c)
        bf2[c] = *(const half8*)(feat_s + l16*136 + 32*c + 8*q);
      const size_t trow = (size_t)(b*Tt + tl0 + l16) * 512;
#pragma unroll
      for (int g = 0; g < 4; ++g){
        f32x4 acc = bias2[g];
#pragma unroll
        for (int c = 0; c < 4; ++c)
          acc = MFMA16(aW2[g][c], bf2[c], acc);
        U2 u;
#pragma unroll
        for (int r = 0; r < 4; ++r) u.h[r] = (f16)acc[r];
        *(uint2*)(zx + trow + g*128 + jq) = u.u;
      }
    }
    __syncthreads();
  }
}

// ---------------------------------------------------------------------------
// Scan v4: 64 WGs x 1 batch. z staged via LDS in 16-step chunks with a
// register-carried 1-chunk lookahead (no per-step VMEM -> no per-step vmcnt
// drain at the barrier). Nonlinearity deduplicated 4x: lane handles only
// r = l16&3 (6 trans ops/lane/step instead of 24).
// ---------------------------------------------------------------------------
__global__ __launch_bounds__(512, 2)
void scan_k(const f16* __restrict__ zx, const float* __restrict__ dt,
            const float* __restrict__ w_ff1, const float* __restrict__ w_ff2,
            const float* __restrict__ w_ta,  const float* __restrict__ w_tb,
            const float* __restrict__ head_w, const float* __restrict__ head_b,
            float* __restrict__ out)
{
  __shared__ __align__(16) f16   zbuf[2][CH*512];  // 2 x 16 KB
  __shared__ __align__(16) f16   h_s[2][Hh];
  __shared__ float dts[Tt];                        // 16 KB
  __shared__ float hp[2][8];

  const int tid  = threadIdx.x;
  const int wv   = tid >> 6;
  const int lane = tid & 63;
  const int q    = lane >> 4;
  const int l16  = lane & 15;
  const int jq   = 16*wv + 4*q;
  const int rr   = l16 & 3;
  const bool sel1 = (rr & 1) != 0;
  const bool sel2 = (rr & 2) != 0;
  const int b    = blockIdx.x;

  const float* Wg[4] = { w_ff1, w_ff2, w_ta, w_tb };
  half8 aW[4][4];                                  // W_bot^T, k rows 128..255
#pragma unroll
  for (int g = 0; g < 4; ++g){
    const float* wp = Wg[g];
    const int jc = 16*wv + l16;
#pragma unroll
    for (int c = 0; c < 4; ++c)
#pragma unroll
      for (int i = 0; i < 8; ++i)
        aW[g][c][i] = (f16)wp[(128 + 32*c + 8*q + i)*Hh + jc];
  }
  const float hw_r = head_w[jq + rr];
  const float hb   = head_b[0];

  for (int i = tid; i < Tt; i += 512) dts[i] = dt[(size_t)b*Tt + i] * 10.0f;
  if (tid < Hh){ h_s[0][tid] = (f16)0.f; h_s[1][tid] = (f16)0.f; }

  const f16* zg = zx + (size_t)b*Tt*512;
  const float4* zg4 = (const float4*)zg;           // chunk = 1024 float4

  // prologue: chunk0 -> regs -> zbuf[0]; chunk1 -> regs
  float4 rz[2];
#pragma unroll
  for (int j = 0; j < 2; ++j) rz[j] = zg4[j*512 + tid];
#pragma unroll
  for (int j = 0; j < 2; ++j) ((float4*)zbuf[0])[j*512 + tid] = rz[j];
#pragma unroll
  for (int j = 0; j < 2; ++j) rz[j] = zg4[1024 + j*512 + tid];
  __syncthreads();   // zbuf[0] + h_s + dts visible; drains chunk1 loads (once)

  const size_t obase = (size_t)b*Tt;

  for (int c = 0; c < Tt/CH; ++c){
    const int cur = c & 1, nxt = cur ^ 1;
    // commit staged regs (chunk c+1) to zbuf[nxt]; refill regs with chunk c+2
#pragma unroll
    for (int j = 0; j < 2; ++j) ((float4*)zbuf[nxt])[j*512 + tid] = rz[j];
    if (c + 2 < Tt/CH){
      const float4* src = zg4 + (size_t)(c+2)*1024;
#pragma unroll
      for (int j = 0; j < 2; ++j) rz[j] = src[j*512 + tid];
    }
    const f16* zl = zbuf[cur];

    for (int s = 0; s < CH; ++s){
      const int t = c*CH + s;
      const int p = t & 1;
      // h fragments (same-address broadcast, conflict-free)
      half8 bf[4];
#pragma unroll
      for (int cc = 0; cc < 4; ++cc)
        bf[cc] = *(const half8*)(&h_s[p][32*cc + 8*q]);
      // z for this lane's own r only
      float zr[4];
#pragma unroll
      for (int g = 0; g < 4; ++g)
        zr[g] = (float)zl[(s << 9) + g*128 + jq + rr];
      const float dtt = dts[t];

      f32x4 accs[4];
#pragma unroll
      for (int g = 0; g < 4; ++g){
        f32x4 a = {0.f, 0.f, 0.f, 0.f};
#pragma unroll
        for (int cc = 0; cc < 4; ++cc)
          a = MFMA16(aW[g][cc], bf[cc], a);
        accs[g] = a;
      }
      // emit out[t-1] while MFMAs are in flight (reads hp[p^1], one step old)
      if (t > 0 && tid < 8){
        float sE = hp[p^1][tid];
        sE += __shfl_xor(sE, 1); sE += __shfl_xor(sE, 2); sE += __shfl_xor(sE, 4);
        if (tid == 0) out[obase + t - 1] = sE + hb;
      }
      // select own r from the 4 acc regs (masks loop-invariant, hoisted)
      float pre[4];
#pragma unroll
      for (int g = 0; g < 4; ++g){
        float s01 = sel1 ? accs[g][1] : accs[g][0];
        float s23 = sel1 ? accs[g][3] : accs[g][2];
        pre[g] = (sel2 ? s23 : s01) + zr[g];
      }
      // CfC cell (one h per lane)
      float u_ = fast_rcp(fast_ex2(L2E2*pre[0]) + 1.0f);   // (1-tanh)/2
      float v_ = fast_rcp(fast_ex2(L2E2*pre[1]) + 1.0f);
      float g_ = fast_rcp(fast_ex2(-L2E*(pre[2]*dtt + pre[3])) + 1.0f);
      float hn = 1.0f - 2.0f*(u_ - g_*(u_ - v_));
      if (l16 < 4) h_s[p^1][jq + l16] = (f16)hn;           // b16 write
      // head partial: sum over r (bits 0-1) and q (bits 4-5); skip dup bits 2-3
      float hpart = hn * hw_r;
      hpart += __shfl_xor(hpart, 1);
      hpart += __shfl_xor(hpart, 2);
      hpart += __shfl_xor(hpart, 16);
      hpart += __shfl_xor(hpart, 32);
      if (lane == 0) hp[p][wv] = hpart;
      __syncthreads();
    }
  }
  // final out[T-1]: parity of t=Tt-1 is 1
  if (tid < 8){
    float sE = hp[1][tid];
    sE += __shfl_xor(sE, 1); sE += __shfl_xor(sE, 2); sE += __shfl_xor(sE, 4);
    if (tid == 0) out[obase + Tt - 1] = sE + hb;
  }
}

extern "C" void kernel_launch(void* const* d_in, const int* in_sizes, int n_in,
                              void* d_out, int out_size, void* d_ws, size_t ws_size,
                              hipStream_t stream)
{
  const float* x       = (const float*)d_in[0];
  const float* dt      = (const float*)d_in[1];
  const float* ln_in_g = (const float*)d_in[2];
  const float* ln_in_b = (const float*)d_in[3];
  const float* proj_w  = (const float*)d_in[4];
  const float* proj_b  = (const float*)d_in[5];
  const float* ln_p_g  = (const float*)d_in[6];
  const float* ln_p_b  = (const float*)d_in[7];
  const float* ff1_w   = (const float*)d_in[8];
  const float* ff1_b   = (const float*)d_in[9];
  const float* ff2_w   = (const float*)d_in[10];
  const float* ff2_b   = (const float*)d_in[11];
  const float* ta_w    = (const float*)d_in[12];
  const float* ta_b    = (const float*)d_in[13];
  const float* tb_w    = (const float*)d_in[14];
  const float* tb_b    = (const float*)d_in[15];
  const float* head_w  = (const float*)d_in[16];
  const float* head_b  = (const float*)d_in[17];

  f16*   zx  = (f16*)d_ws;      // [b][t][n] fp16 = 256 MiB
  float* out = (float*)d_out;

  stage_a<<<dim3(256), dim3(512), 0, stream>>>(
      x, ln_in_g, ln_in_b, proj_w, proj_b, ln_p_g, ln_p_b,
      ff1_w, ff1_b, ff2_w, ff2_b, ta_w, ta_b, tb_w, tb_b, zx);

  scan_k<<<dim3(Bb), dim3(512), 0, stream>>>(
      zx, dt, ff1_w, ff2_w, ta_w, tb_w, head_w, head_b, out);
}